// Round 16
// baseline (548.057 us; speedup 1.0000x reference)
//
#include <hip/hip_runtime.h>
#include <cstdint>
#include <cstddef>

// Problem shape (fixed by the reference): B=8, C=192, Tx=512, Ty=2048.
#define BB 8
#define CC 192
#define TXX 512
#define TYY 2048

#define NEG_INF (-1e9f)
#define HALF_LOG_2PI 0.9189385332046727f  // 0.5*log(2*pi)

// ---- output layout (floats, concatenated in return order) ----
#define O1 8388608
#define O2 11534336
#define O3 14680064
#define O4 14680065

// ---- workspace layout (bytes) ----
#define WS_NEG   0           // neg_cent fp32 [B,Ty,Tx]           33,554,432 B
#define WS_S     33554432    // s_p_sq_r [B,C,Tx]                  3,145,728 B
#define WS_MSR   36700160    // m_p * s  [B,C,Tx]                  3,145,728 B
#define WS_BIAS  39845888    // nc1+nc4  [B,Tx]                       16,384 B
#define WS_DIRS  39862272    // dir bits [B,Ty/4,64] dwords        1,048,576 B
#define WS_IDX   40910848    // idx_map  [B,Ty] int                   65,536 B
#define WS_LENS  40976384    // int text_len[8], spec_len[8]             64 B
#define WS_PART  40976448    // kl partials [3072] float              12,288 B

typedef float f32x4 __attribute__((ext_vector_type(4)));

// ---------------------------------------------------------------------------
// k_pre (R28): fused prep + bias + len (zero lives in k_gz to overlap with
// gemm). bias recomputes msv with the IDENTICAL expression tree as prep
// stores (bitwise-same), so no prep->bias dependency.
// ---------------------------------------------------------------------------
#define PRE_NPREP 3072
#define PRE_NBIAS 16
#define PRE_NLEN  8
__global__ __launch_bounds__(256) void k_pre(const float* __restrict__ logs_p,
                                             const float* __restrict__ m_p,
                                             const float* __restrict__ tmask,
                                             const float* __restrict__ smask,
                                             float* __restrict__ s,
                                             float* __restrict__ msr,
                                             float* __restrict__ bias,
                                             int* __restrict__ lens) {
    int blk = blockIdx.x, tid = threadIdx.x;
    if (blk < PRE_NPREP) {
        int i = blk * 256 + tid;
        float lp = logs_p[i], m = m_p[i];
        float sv = expf(-2.0f * lp);
        s[i] = sv;
        msr[i] = m * sv;
    } else if (blk < PRE_NPREP + PRE_NBIAS) {
        int i = (blk - PRE_NPREP) * 256 + tid;  // B*Tx = 4096
        int b = i >> 9, x = i & (TXX - 1);
        size_t base = (size_t)b * CC * TXX + x;
        const float* lpb = logs_p + base;
        const float* mb  = m_p + base;
        float acc = 0.f;
#pragma unroll 8
        for (int c = 0; c < CC; ++c) {
            float lp = lpb[(size_t)c * TXX];
            float m  = mb[(size_t)c * TXX];
            float msv = m * expf(-2.0f * lp);   // == msr[c] bitwise
            acc += -HALF_LOG_2PI - lp - 0.5f * m * msv;
        }
        bias[i] = acc;
    } else {
        __shared__ float red[256];
        int b = blk - (PRE_NPREP + PRE_NBIAS);
        float ts = 0.f;
        for (int i = tid; i < TXX; i += 256) ts += tmask[b * TXX + i];
        red[tid] = ts; __syncthreads();
        for (int s2 = 128; s2 > 0; s2 >>= 1) { if (tid < s2) red[tid] += red[tid + s2]; __syncthreads(); }
        if (tid == 0) lens[b] = (int)(red[0] + 0.5f);
        __syncthreads();
        float ss = 0.f;
        for (int i = tid; i < TYY; i += 256) ss += smask[b * TYY + i];
        red[tid] = ss; __syncthreads();
        for (int s2 = 128; s2 > 0; s2 >>= 1) { if (tid < s2) red[tid] += red[tid + s2]; __syncthreads(); }
        if (tid == 0) lens[8 + b] = (int)(red[0] + 0.5f);
    }
}

// ---------------------------------------------------------------------------
// k_gz (R29, proven): zero blocks (0..511) + 64x64 gemm with register
// double-buffered staging (512..2559). Bitwise-identical neg.
// ---------------------------------------------------------------------------
#define GZ_NZERO 512
__global__ __launch_bounds__(256) void k_gz(const float* __restrict__ z,
                                            const float* __restrict__ msr,
                                            const float* __restrict__ sarr,
                                            const float* __restrict__ bias,
                                            const int* __restrict__ lens,
                                            float* __restrict__ neg,
                                            float* __restrict__ out) {
    int id = blockIdx.x, tid = threadIdx.x;
    if (id < GZ_NZERO) {
        int64_t i = (int64_t)id * 256 + tid;
        const int64_t n4 = (int64_t)BB * TYY * TXX / 4;
        float4 z4 = make_float4(0.f, 0.f, 0.f, 0.f);
        float4* p4 = (float4*)out;
        for (int64_t k = i; k < n4; k += (int64_t)GZ_NZERO * 256) p4[k] = z4;
        if (i < BB * TXX) out[O4 + i] = 0.0f;
        return;
    }
    int gid = id - GZ_NZERO;
    int x0 = (gid & 7) * 64, t0 = ((gid >> 3) & 31) * 64, b = gid >> 8;
    if (x0 >= lens[b] || t0 >= lens[8 + b]) return;   // masked tile

    __shared__ float Zs[16][68], Ms[16][68], Ss[16][68];  // +4 pad
    int tx = tid & 15, ty = tid >> 4;
    const float* zb = z    + (size_t)b * CC * TYY;
    const float* mb = msr  + (size_t)b * CC * TXX;
    const float* sb = sarr + (size_t)b * CC * TXX;
    int lr = tid >> 4, lc = (tid & 15) * 4;
    float acc[4][4] = {};
    float4 zv = *(const float4*)(zb + (size_t)lr * TYY + t0 + lc);
    float4 mv = *(const float4*)(mb + (size_t)lr * TXX + x0 + lc);
    float4 sv = *(const float4*)(sb + (size_t)lr * TXX + x0 + lc);
    for (int k0 = 0; k0 < CC; k0 += 16) {
        __syncthreads();
        *(float4*)&Zs[lr][lc] = zv;
        *(float4*)&Ms[lr][lc] = mv;
        *(float4*)&Ss[lr][lc] = sv;
        __syncthreads();
        if (k0 + 16 < CC) {
            zv = *(const float4*)(zb + (size_t)(k0 + 16 + lr) * TYY + t0 + lc);
            mv = *(const float4*)(mb + (size_t)(k0 + 16 + lr) * TXX + x0 + lc);
            sv = *(const float4*)(sb + (size_t)(k0 + 16 + lr) * TXX + x0 + lc);
        }
#pragma unroll
        for (int k = 0; k < 16; ++k) {
            float4 a4  = *(const float4*)&Zs[k][ty * 4];
            float4 bm4 = *(const float4*)&Ms[k][tx * 4];
            float4 bs4 = *(const float4*)&Ss[k][tx * 4];
            float av[4]  = {a4.x, a4.y, a4.z, a4.w};
            float bmv[4] = {bm4.x, bm4.y, bm4.z, bm4.w};
            float bsv[4] = {bs4.x, bs4.y, bs4.z, bs4.w};
#pragma unroll
            for (int i2 = 0; i2 < 4; ++i2) {
                float a2 = -0.5f * av[i2] * av[i2];
#pragma unroll
                for (int j = 0; j < 4; ++j)
                    acc[i2][j] += av[i2] * bmv[j] + a2 * bsv[j];
            }
        }
    }
    float4 b4 = *(const float4*)(bias + b * TXX + x0 + tx * 4);
    float bv[4] = {b4.x, b4.y, b4.z, b4.w};
#pragma unroll
    for (int i2 = 0; i2 < 4; ++i2) {
        int t = t0 + ty * 4 + i2;
        float4 o;
        o.x = acc[i2][0] + bv[0]; o.y = acc[i2][1] + bv[1];
        o.z = acc[i2][2] + bv[2]; o.w = acc[i2][3] + bv[3];
        *(float4*)(neg + ((size_t)b * TYY + t) * TXX + x0 + tx * 4) = o;
    }
}

// ---------------------------------------------------------------------------
// MAS forward v13 (R30): TWO waves (x-split 256/256), FLAG-synced (no
// barriers), v5-style asm-pinned per-wave prefetch.
//
// R29 counters: fwd is issue-bound (per-SIMD VALUBusy ~65%, ~142cy/row of
// serial single-wave issue; dep chain only ~12cy/row). v10 proved the
// 2-wave DP math + dirs layout (passed) but died on 257 s_barrier drains.
// v13 replaces barriers with LDS flags:
//   - loads need NO sync (neg fully written by k_gz): each wave prefetches
//     its own 256-col half, v5 pattern (8 GLOAD4/group, 3 buffers, 96 VGPR).
//   - boundary: A writes bnd[y&63] (64-deep ring) per row; after group g,
//     lgkmcnt(0) + release flagA=g+1. B acquire-polls flagA>=g+1, then
//     reads bnv[8]. A back-pressure-polls flagB>=g-6 (ring depth 8 groups;
//     trivially true in steady state).
//   - deadlock-free: A runs groups 0..6 unconditionally; induction flows.
//   - vmcnt ladder (8 loads + 2 dirs stores/group): newer-than-L(g) at the
//     wait = 2+8+2+8 = 20 steady (16 for g<2: prologue has only L(g+1)8 +
//     L(g+2)8 newer); tails 12 / 4.
// dirs layout bit-identical to v5/v10 (k_bwd unchanged).
// ---------------------------------------------------------------------------
#define GLOAD4(DST, PTR, OFF)                                             \
    asm volatile("global_load_dwordx4 %0, %1, off offset:" #OFF           \
                 : "=v"(DST) : "v"(PTR) : "memory")

#define GLOADD(DST, PTR)                                                  \
    asm volatile("global_load_dword %0, %1, off"                          \
                 : "=v"(DST) : "v"(PTR) : "memory")

#define WAIT_VM(N) do {                                                   \
    asm volatile("s_waitcnt vmcnt(" #N ")" ::: "memory");                 \
    __builtin_amdgcn_sched_barrier(0);                                    \
} while (0)

// 8 rows x 256 floats (own half); lane owns 16B (one float4) per row.
#define LOADG(DST, G) do {                                                \
    const char* p0_ = ncb + (size_t)(G) * 16384;                          \
    const char* p2_ = p0_ + 4096;                                         \
    const char* p4_ = p0_ + 8192;                                         \
    const char* p6_ = p0_ + 12288;                                        \
    GLOAD4(DST[0], p0_, 0); GLOAD4(DST[1], p0_, 2048);                    \
    GLOAD4(DST[2], p2_, 0); GLOAD4(DST[3], p2_, 2048);                    \
    GLOAD4(DST[4], p4_, 0); GLOAD4(DST[5], p4_, 2048);                    \
    GLOAD4(DST[6], p6_, 0); GLOAD4(DST[7], p6_, 2048);                    \
} while (0)

#define POLL_GE(FLAG, VAL) do {                                           \
    while (__hip_atomic_load(&(FLAG), __ATOMIC_ACQUIRE,                   \
                             __HIP_MEMORY_SCOPE_WORKGROUP) < (VAL))       \
        __builtin_amdgcn_s_sleep(1);                                      \
    __builtin_amdgcn_sched_barrier(0);                                    \
} while (0)

#define SET_FLAG(FLAG, VAL) do {                                          \
    asm volatile("s_waitcnt lgkmcnt(0)" ::: "memory");                    \
    __builtin_amdgcn_sched_barrier(0);                                    \
    if (lane == 0)                                                        \
        __hip_atomic_store(&(FLAG), (VAL), __ATOMIC_RELEASE,              \
                           __HIP_MEMORY_SCOPE_WORKGROUP);                 \
} while (0)

// One DP row, 4 cols/lane (v10-proven math + dirs merge). pl via DPP shr1
// with old=NEG_INF (covers A lane0); B lane0 overridden with bnv[R].
#define DPR4(BUF, R, YB) do {                                                 \
    f32x4 q_ = BUF[R];                                                        \
    unsigned d_ = 0;                                                          \
    float pl_ = __int_as_float(__builtin_amdgcn_update_dpp(                   \
        ninf_i, __float_as_int(v[3]), 0x138, 0xF, 0xF, false));               \
    if (!isA && lane == 0) pl_ = bnv[R];                                      \
    float n0_ = q_[0] + fmaxf(v[0], pl_);  if (pl_  > v[0]) d_ |= 1u;         \
    float n1_ = q_[1] + fmaxf(v[1], v[0]); if (v[0] > v[1]) d_ |= 2u;         \
    float n2_ = q_[2] + fmaxf(v[2], v[1]); if (v[1] > v[2]) d_ |= 4u;         \
    float n3_ = q_[3] + fmaxf(v[3], v[2]); if (v[2] > v[3]) d_ |= 8u;         \
    v[0] = n0_; v[1] = n1_; v[2] = n2_; v[3] = n3_;                           \
    unsigned t_ = (unsigned)((YB) + (R) - xb4);                               \
    if (t_ < 4u) d_ |= 1u << t_;          /* fold x==y */                     \
    unsigned dl_ = (unsigned)__builtin_amdgcn_update_dpp(                     \
        0, (int)d_, 0x138, 0xF, 0xF, false);                                  \
    acc |= ((d_ << 4) | dl_) << (((R) & 3) * 8);                              \
    if (isA && lane == 63) bnd[((YB) + (R)) & 63] = v[3];                     \
} while (0)

// Row y==0: only x==0 scored (A lane0); no DP.
#define DPR0(Q0) do {                                                         \
    if (isA && lane == 0) v[0] = Q0[0];                                       \
    unsigned d_ = (isA && lane == 0) ? 1u : 0u;                               \
    unsigned dl_ = (unsigned)__builtin_amdgcn_update_dpp(                     \
        0, (int)d_, 0x138, 0xF, 0xF, false);                                  \
    acc |= (d_ << 4) | dl_;                                                   \
    if (isA && lane == 63) bnd[0] = v[3];                                     \
} while (0)

#define FWD_ITER(G, CUR, NXT) do {                                            \
    int g_ = (G);                                                             \
    if (g_ + 2 < ng) LOADG(NXT, g_ + 2);   /* issue before poll */            \
    if (isA) { POLL_GE(flagB, g_ - 6); }                                      \
    else     { POLL_GE(flagA, g_ + 1); }                                      \
    float bnv[8];                                                             \
    {   int bb_ = 8 * g_ - 1;                                                 \
        _Pragma("unroll")                                                     \
        for (int k_ = 0; k_ < 8; ++k_) bnv[k_] = bnd[(bb_ + k_) & 63]; }      \
    __builtin_amdgcn_sched_barrier(0);                                        \
    if (g_ + 2 < ng) { if (g_ < 2) { WAIT_VM(16); } else { WAIT_VM(20); } }   \
    else if (g_ + 1 < ng) { WAIT_VM(12); }                                    \
    else { WAIT_VM(4); }                                                      \
    int yb_ = 8 * g_;                                                         \
    uint32_t* dp_ = db32 + ((unsigned)g_ << 7) + woff + (lane >> 1);          \
    if (yb_ == 0) {                                                           \
        DPR0(CUR[0]);                                                         \
        DPR4(CUR, 1, yb_); DPR4(CUR, 2, yb_); DPR4(CUR, 3, yb_);              \
    } else {                                                                  \
        DPR4(CUR, 0, yb_); DPR4(CUR, 1, yb_);                                 \
        DPR4(CUR, 2, yb_); DPR4(CUR, 3, yb_);                                 \
    }                                                                         \
    if (lane & 1) dp_[0] = acc;                                               \
    acc = 0;                                                                  \
    DPR4(CUR, 4, yb_); DPR4(CUR, 5, yb_);                                     \
    DPR4(CUR, 6, yb_); DPR4(CUR, 7, yb_);                                     \
    if (lane & 1) dp_[64] = acc;                                              \
    acc = 0;                                                                  \
    if (isA) { SET_FLAG(flagA, g_ + 1); }                                     \
    else     { SET_FLAG(flagB, g_ + 1); }                                     \
} while (0)

__global__ __launch_bounds__(128, 1) void k_fwd(const float* __restrict__ neg,
                                                const int* __restrict__ lens,
                                                uint32_t* __restrict__ dirs) {
    __shared__ float bnd[64];     // A->B boundary ring (8 groups deep)
    __shared__ int flagA, flagB;  // groups completed by A / by B
    int b = blockIdx.x, tid = threadIdx.x;
    int wave = tid >> 6, lane = tid & 63;
    bool isA = (wave == 0);
    if (tid == 0) { flagA = 0; flagB = 0; }
    __syncthreads();              // one-time init barrier

    int xhalf = isA ? 0 : 1024;   // byte offset of own half-row
    int xb4 = (isA ? 0 : 256) + 4 * lane;
    int woff = isA ? 0 : 32;
    const char* ncb = (const char*)(neg + (size_t)b * TYY * TXX)
                      + xhalf + lane * 16;
    uint32_t* db32 = dirs + (size_t)b * (TYY / 4) * 64;
    int slen = lens[8 + b];
    int ng = (slen + 7) >> 3;     // 192..256 (slen >= 1536)
    int ninf_i = __float_as_int(NEG_INF);

    float v[4];
#pragma unroll
    for (int j = 0; j < 4; ++j) v[j] = NEG_INF;
    unsigned acc = 0;

    f32x4 bufA[8], bufB[8], bufC[8];  // 3 groups in flight (96 VGPR)
    LOADG(bufA, 0);
    LOADG(bufB, 1);

    for (int p = 0; p < ng; p += 3) {
        FWD_ITER(p, bufA, bufC);
        if (p + 1 < ng) FWD_ITER(p + 1, bufB, bufA);
        if (p + 2 < ng) FWD_ITER(p + 2, bufC, bufB);
    }
}

// ---------------------------------------------------------------------------
// MAS backtrack v3 (R28, proven): truly deferred packing; raw loads issued
// before the 32-step chain, packed after vmcnt(0) once latency is covered.
// Scatter + duration fused in the store step.
// ---------------------------------------------------------------------------
#define RAWLD(NR, WB, QROW) do {                                          \
    const uint32_t* p_ = db32 + (QROW) + 4 * (WB);                        \
    GLOADD(NR[0],  (p_ + 0));  GLOADD(NR[1],  (p_ + 1));                  \
    GLOADD(NR[2],  (p_ + 2));  GLOADD(NR[3],  (p_ + 3));                  \
    GLOADD(NR[4],  (p_ + 4));  GLOADD(NR[5],  (p_ + 5));                  \
    GLOADD(NR[6],  (p_ + 6));  GLOADD(NR[7],  (p_ + 7));                  \
    GLOADD(NR[8],  (p_ + 8));  GLOADD(NR[9],  (p_ + 9));                  \
    GLOADD(NR[10], (p_ + 10)); GLOADD(NR[11], (p_ + 11));                 \
} while (0)

#define PACKW(W0, W1, W2, NR, BOFF) do {                                  \
    W0 = ((NR[0]>>(BOFF))&0xffu)        | (((NR[1]>>(BOFF))&0xffu)<<8) |  \
         (((NR[2]>>(BOFF))&0xffu)<<16)  | (((NR[3]>>(BOFF))&0xffu)<<24);  \
    W1 = ((NR[4]>>(BOFF))&0xffu)        | (((NR[5]>>(BOFF))&0xffu)<<8) |  \
         (((NR[6]>>(BOFF))&0xffu)<<16)  | (((NR[7]>>(BOFF))&0xffu)<<24);  \
    W2 = ((NR[8]>>(BOFF))&0xffu)        | (((NR[9]>>(BOFF))&0xffu)<<8) |  \
         (((NR[10]>>(BOFF))&0xffu)<<16) | (((NR[11]>>(BOFF))&0xffu)<<24); \
} while (0)

__global__ __launch_bounds__(64, 1) void k_bwd(const int* __restrict__ lens,
                                               const uint32_t* __restrict__ dirs,
                                               int* __restrict__ idx_map,
                                               float* __restrict__ out) {
    int b = blockIdx.x, lane = threadIdx.x;
    const uint32_t* db32 = dirs + (size_t)b * (TYY / 4) * 64;
    int tlen = lens[b], slen = lens[8 + b];

    int idx = tlen - 1;
    int y0 = slen - 1;
    int wb;
    uint32_t W0 = 0, W1 = 0, W2 = 0;
    {   // prologue: slab-0 window (one unavoidable stall)
        int yy = y0 - lane; if (yy < 0) yy = 0;
        int qrow = (yy >> 2) * 64, boff = (yy & 3) * 8;
        int t = (idx >> 5) - 1; if (t < 0) t = 0; if (t > 13) t = 13;
        wb = t;
        uint32_t R[12];
        if (lane < 32) {
            RAWLD(R, wb, qrow);
            asm volatile("s_waitcnt vmcnt(0)" ::: "memory");
            __builtin_amdgcn_sched_barrier(0);
            PACKW(W0, W1, W2, R, boff);
        }
    }
    while (y0 >= 0) {
        int w0 = (idx >> 5) - 1; if (w0 < 0) w0 = 0; if (w0 > 14) w0 = 14;
        int s = w0 - wb; if (s < 0) s = 0; if (s > 1) s = 1;
        uint32_t lo = s ? W1 : W0;
        uint32_t hi = s ? W2 : W1;
        int base = (wb + s) << 5;
        // ---- issue next slab's RAW loads (latency hides under the chain) --
        uint32_t N[12];
        int idxm = idx - 32; if (idxm < 0) idxm = 0;
        int wbn = (idxm >> 5) - 1; if (wbn < 0) wbn = 0; if (wbn > 13) wbn = 13;
        int yn = y0 - 32 - lane; if (yn < 0) yn = 0;
        int qn = (yn >> 2) * 64, bn = (yn & 3) * 8;
        if (lane < 32) RAWLD(N, wbn, qn);
        __builtin_amdgcn_sched_barrier(0);
        // ---- 32-step chain ----
        int nsteps = (y0 + 1 < 32) ? y0 + 1 : 32;
        int cap = 0;
#pragma unroll
        for (int j = 0; j < 32; ++j) {
            if (lane == j) cap = idx;
            uint32_t l = (uint32_t)__builtin_amdgcn_readlane((int)lo, j);
            uint32_t h = (uint32_t)__builtin_amdgcn_readlane((int)hi, j);
            int bp = idx - base;              // 0..63 within slab
            uint32_t word = (bp & 32) ? h : l;
            idx -= (int)((word >> (bp & 31)) & 1u);
        }
        __builtin_amdgcn_sched_barrier(0);
        asm volatile("s_waitcnt vmcnt(0)" ::: "memory");   // N landed
        __builtin_amdgcn_sched_barrier(0);
        PACKW(W0, W1, W2, N, bn);
        wb = wbn;
        if (lane < nsteps) {
            int y = y0 - lane;
            idx_map[b * TYY + y] = cap;
            out[((size_t)(b * TYY + y)) * TXX + cap] = 1.0f;       // scatter
            atomicAdd(&out[O4 + b * TXX + cap], 1.0f);             // duration
        }
        y0 -= 32;
    }
}

// Gather m_p/logs_p onto spec frames via idx_map; fused KL partial sums.
__global__ __launch_bounds__(256) void k_gather(const float* __restrict__ z_p,
                                                const float* __restrict__ m_p,
                                                const float* __restrict__ logs_p,
                                                const float* __restrict__ logs_q,
                                                const int* __restrict__ lens,
                                                const int* __restrict__ idx_map,
                                                float* __restrict__ out,
                                                float* __restrict__ partials) {
    const int S = BB * CC * TYY / 4;
    int base = blockIdx.x * 256 + threadIdx.x;
    float klsum = 0.f;
#pragma unroll
    for (int r = 0; r < 4; ++r) {
        int i = base + r * S;
        int t = i & (TYY - 1);
        int bc = i >> 11;
        int b = bc / CC;
        float ma = 0.f, la = 0.f;
        if (t < lens[8 + b]) {
            int x = idx_map[b * TYY + t];
            size_t off = (size_t)bc * TXX + x;
            ma = m_p[off];
            la = logs_p[off];
            float zv = z_p[i], lq = logs_q[i];
            float dz = zv - ma;
            klsum += la - lq - 0.5f + 0.5f * dz * dz * expf(-2.0f * la);
        }
        out[O1 + i] = ma;
        out[O2 + i] = la;
    }
    for (int o = 32; o > 0; o >>= 1) klsum += __shfl_down(klsum, o);
    __shared__ float red[4];
    if ((threadIdx.x & 63) == 0) red[threadIdx.x >> 6] = klsum;
    __syncthreads();
    if (threadIdx.x == 0) partials[blockIdx.x] = red[0] + red[1] + red[2] + red[3];
}

__global__ void k_final(const float* __restrict__ partials, const int* __restrict__ lens,
                        float* __restrict__ out) {
    float s = 0.f;
    for (int i = threadIdx.x; i < 3072; i += 256) s += partials[i];
    for (int o = 32; o > 0; o >>= 1) s += __shfl_down(s, o);
    __shared__ float red[4];
    if ((threadIdx.x & 63) == 0) red[threadIdx.x >> 6] = s;
    __syncthreads();
    if (threadIdx.x == 0) {
        float tot = 0.f;
        for (int b = 0; b < 8; ++b) tot += (float)lens[8 + b];
        out[O3] = (red[0] + red[1] + red[2] + red[3]) / tot;
    }
}

extern "C" void kernel_launch(void* const* d_in, const int* in_sizes, int n_in,
                              void* d_out, int out_size, void* d_ws, size_t ws_size,
                              hipStream_t stream) {
    const float* z_p    = (const float*)d_in[0];
    const float* m_p    = (const float*)d_in[1];
    const float* logs_p = (const float*)d_in[2];
    const float* logs_q = (const float*)d_in[3];
    const float* tmask  = (const float*)d_in[4];
    const float* smask  = (const float*)d_in[5];
    float* out = (float*)d_out;
    char* ws = (char*)d_ws;

    float*    neg      = (float*)(ws + WS_NEG);
    float*    sarr     = (float*)(ws + WS_S);
    float*    msr      = (float*)(ws + WS_MSR);
    float*    bias     = (float*)(ws + WS_BIAS);
    uint32_t* dirs     = (uint32_t*)(ws + WS_DIRS);
    int*      idx_map  = (int*)(ws + WS_IDX);
    int*      lens     = (int*)(ws + WS_LENS);
    float*    partials = (float*)(ws + WS_PART);

    hipLaunchKernelGGL(k_pre,    dim3(PRE_NPREP + PRE_NBIAS + PRE_NLEN),
                       dim3(256), 0, stream,
                       logs_p, m_p, tmask, smask, sarr, msr, bias, lens);
    hipLaunchKernelGGL(k_gz,     dim3(GZ_NZERO + 2048), dim3(256), 0, stream,
                       z_p, msr, sarr, bias, lens, neg, out);
    hipLaunchKernelGGL(k_fwd,    dim3(8),        dim3(128), 0, stream, neg, lens, dirs);
    hipLaunchKernelGGL(k_bwd,    dim3(8),        dim3(64),  0, stream, lens, dirs, idx_map, out);
    hipLaunchKernelGGL(k_gather, dim3(3072),     dim3(256), 0, stream,
                       z_p, m_p, logs_p, logs_q, lens, idx_map, out, partials);
    hipLaunchKernelGGL(k_final,  dim3(1),        dim3(256), 0, stream, partials, lens, out);
}

// Round 17
// 512.421 us; speedup vs baseline: 1.0695x; 1.0695x over previous
//
#include <hip/hip_runtime.h>
#include <cstdint>
#include <cstddef>

// Problem shape (fixed by the reference): B=8, C=192, Tx=512, Ty=2048.
#define BB 8
#define CC 192
#define TXX 512
#define TYY 2048

#define NEG_INF (-1e9f)
#define HALF_LOG_2PI 0.9189385332046727f  // 0.5*log(2*pi)

// ---- output layout (floats, concatenated in return order) ----
#define O1 8388608
#define O2 11534336
#define O3 14680064
#define O4 14680065

// ---- workspace layout (bytes) ----
#define WS_NEG   0           // neg_cent fp32 [B,Ty,Tx]           33,554,432 B
#define WS_S     33554432    // s_p_sq_r [B,C,Tx]                  3,145,728 B
#define WS_MSR   36700160    // m_p * s  [B,C,Tx]                  3,145,728 B
#define WS_BIAS  39845888    // nc1+nc4  [B,Tx]                       16,384 B
#define WS_DIRS  39862272    // dir bits [B,Ty/4,64] dwords        1,048,576 B
#define WS_IDX   40910848    // idx_map  [B,Ty] int                   65,536 B
#define WS_LENS  40976384    // int text_len[8], spec_len[8]             64 B
#define WS_PART  40976448    // kl partials [3072] float              12,288 B

typedef float f32x4 __attribute__((ext_vector_type(4)));

// ---------------------------------------------------------------------------
// k_pre (R28, proven): fused prep + bias + len. bias recomputes msv with the
// IDENTICAL expression tree as prep stores (bitwise-same).
// ---------------------------------------------------------------------------
#define PRE_NPREP 3072
#define PRE_NBIAS 16
#define PRE_NLEN  8
__global__ __launch_bounds__(256) void k_pre(const float* __restrict__ logs_p,
                                             const float* __restrict__ m_p,
                                             const float* __restrict__ tmask,
                                             const float* __restrict__ smask,
                                             float* __restrict__ s,
                                             float* __restrict__ msr,
                                             float* __restrict__ bias,
                                             int* __restrict__ lens) {
    int blk = blockIdx.x, tid = threadIdx.x;
    if (blk < PRE_NPREP) {
        int i = blk * 256 + tid;
        float lp = logs_p[i], m = m_p[i];
        float sv = expf(-2.0f * lp);
        s[i] = sv;
        msr[i] = m * sv;
    } else if (blk < PRE_NPREP + PRE_NBIAS) {
        int i = (blk - PRE_NPREP) * 256 + tid;  // B*Tx = 4096
        int b = i >> 9, x = i & (TXX - 1);
        size_t base = (size_t)b * CC * TXX + x;
        const float* lpb = logs_p + base;
        const float* mb  = m_p + base;
        float acc = 0.f;
#pragma unroll 8
        for (int c = 0; c < CC; ++c) {
            float lp = lpb[(size_t)c * TXX];
            float m  = mb[(size_t)c * TXX];
            float msv = m * expf(-2.0f * lp);   // == msr[c] bitwise
            acc += -HALF_LOG_2PI - lp - 0.5f * m * msv;
        }
        bias[i] = acc;
    } else {
        __shared__ float red[256];
        int b = blk - (PRE_NPREP + PRE_NBIAS);
        float ts = 0.f;
        for (int i = tid; i < TXX; i += 256) ts += tmask[b * TXX + i];
        red[tid] = ts; __syncthreads();
        for (int s2 = 128; s2 > 0; s2 >>= 1) { if (tid < s2) red[tid] += red[tid + s2]; __syncthreads(); }
        if (tid == 0) lens[b] = (int)(red[0] + 0.5f);
        __syncthreads();
        float ss = 0.f;
        for (int i = tid; i < TYY; i += 256) ss += smask[b * TYY + i];
        red[tid] = ss; __syncthreads();
        for (int s2 = 128; s2 > 0; s2 >>= 1) { if (tid < s2) red[tid] += red[tid + s2]; __syncthreads(); }
        if (tid == 0) lens[8 + b] = (int)(red[0] + 0.5f);
    }
}

// ---------------------------------------------------------------------------
// k_gz v3 (R31): zero blocks (0..511) + 64x64 gemm, 128 THREADS, 4x8 acc.
//
// Ledger: gemm ~150-180us (never in top-5 so <187) vs LDS-BW floor 61us at
// the old 0.75 B/FLOP. R24's failure mode was GRID shrink (occupancy
// collapse), not acc size. v3 keeps the 2048-block grid + 64x64 tile and
// halves LDS traffic: 128 threads x (4x,8t) outputs; per-k reads
// za(32B)+bm4(16B)+bs4(16B) = 64B for 128 FLOP = 0.5 B/FLOP -> 3.2GB ->
// ~41us LDS floor. 2-wave barriers (cheaper drains), 16 waves/CU.
// Per-output FMA order unchanged (k0 asc, k asc, same fma pairing) ->
// BITWISE-IDENTICAL neg. Register double-buffered staging (R29-proven).
// ---------------------------------------------------------------------------
#define GZ_NZERO 512
__global__ __launch_bounds__(128) void k_gz(const float* __restrict__ z,
                                            const float* __restrict__ msr,
                                            const float* __restrict__ sarr,
                                            const float* __restrict__ bias,
                                            const int* __restrict__ lens,
                                            float* __restrict__ neg,
                                            float* __restrict__ out) {
    int id = blockIdx.x, tid = threadIdx.x;
    if (id < GZ_NZERO) {
        int64_t i = (int64_t)id * 128 + tid;
        const int64_t n4 = (int64_t)BB * TYY * TXX / 4;
        float4 z4 = make_float4(0.f, 0.f, 0.f, 0.f);
        float4* p4 = (float4*)out;
        for (int64_t k = i; k < n4; k += (int64_t)GZ_NZERO * 128) p4[k] = z4;
        if (i < BB * TXX) out[O4 + i] = 0.0f;
        return;
    }
    int gid = id - GZ_NZERO;
    int x0 = (gid & 7) * 64, t0 = ((gid >> 3) & 31) * 64, b = gid >> 8;
    if (x0 >= lens[b] || t0 >= lens[8 + b]) return;   // masked tile

    __shared__ float Zs[16][68], Ms[16][68], Ss[16][68];  // +4 pad
    int tx = tid & 15, ty = tid >> 4;        // tx: x/4 (0..15), ty: t/8 (0..7)
    const float* zb = z    + (size_t)b * CC * TYY;
    const float* mb = msr  + (size_t)b * CC * TXX;
    const float* sb = sarr + (size_t)b * CC * TXX;
    int lr = tid >> 4, lc = (tid & 15) * 4;  // stage rows lr, lr+8
    float acc[8][4] = {};
    // preload K-step 0 (6 float4)
    float4 zv0 = *(const float4*)(zb + (size_t)lr * TYY + t0 + lc);
    float4 zv1 = *(const float4*)(zb + (size_t)(lr + 8) * TYY + t0 + lc);
    float4 mv0 = *(const float4*)(mb + (size_t)lr * TXX + x0 + lc);
    float4 mv1 = *(const float4*)(mb + (size_t)(lr + 8) * TXX + x0 + lc);
    float4 sv0 = *(const float4*)(sb + (size_t)lr * TXX + x0 + lc);
    float4 sv1 = *(const float4*)(sb + (size_t)(lr + 8) * TXX + x0 + lc);
    for (int k0 = 0; k0 < CC; k0 += 16) {
        __syncthreads();
        *(float4*)&Zs[lr][lc]     = zv0;
        *(float4*)&Zs[lr + 8][lc] = zv1;
        *(float4*)&Ms[lr][lc]     = mv0;
        *(float4*)&Ms[lr + 8][lc] = mv1;
        *(float4*)&Ss[lr][lc]     = sv0;
        *(float4*)&Ss[lr + 8][lc] = sv1;
        __syncthreads();
        if (k0 + 16 < CC) {   // issue next K-step's loads BEFORE compute
            zv0 = *(const float4*)(zb + (size_t)(k0 + 16 + lr) * TYY + t0 + lc);
            zv1 = *(const float4*)(zb + (size_t)(k0 + 24 + lr) * TYY + t0 + lc);
            mv0 = *(const float4*)(mb + (size_t)(k0 + 16 + lr) * TXX + x0 + lc);
            mv1 = *(const float4*)(mb + (size_t)(k0 + 24 + lr) * TXX + x0 + lc);
            sv0 = *(const float4*)(sb + (size_t)(k0 + 16 + lr) * TXX + x0 + lc);
            sv1 = *(const float4*)(sb + (size_t)(k0 + 24 + lr) * TXX + x0 + lc);
        }
#pragma unroll
        for (int k = 0; k < 16; ++k) {
            float4 za  = *(const float4*)&Zs[k][ty * 8];
            float4 zb4 = *(const float4*)&Zs[k][ty * 8 + 4];
            float4 bm4 = *(const float4*)&Ms[k][tx * 4];
            float4 bs4 = *(const float4*)&Ss[k][tx * 4];
            float zt[8]  = {za.x, za.y, za.z, za.w, zb4.x, zb4.y, zb4.z, zb4.w};
            float bmv[4] = {bm4.x, bm4.y, bm4.z, bm4.w};
            float bsv[4] = {bs4.x, bs4.y, bs4.z, bs4.w};
#pragma unroll
            for (int i2 = 0; i2 < 8; ++i2) {
                float a = zt[i2];
                float a2 = -0.5f * a * a;
#pragma unroll
                for (int j = 0; j < 4; ++j)
                    acc[i2][j] += a * bmv[j] + a2 * bsv[j];
            }
        }
    }
    float4 b4 = *(const float4*)(bias + b * TXX + x0 + tx * 4);
    float bv[4] = {b4.x, b4.y, b4.z, b4.w};
#pragma unroll
    for (int i2 = 0; i2 < 8; ++i2) {
        int t = t0 + ty * 8 + i2;
        float4 o;
        o.x = acc[i2][0] + bv[0]; o.y = acc[i2][1] + bv[1];
        o.z = acc[i2][2] + bv[2]; o.w = acc[i2][3] + bv[3];
        *(float4*)(neg + ((size_t)b * TYY + t) * TXX + x0 + tx * 4) = o;
    }
}

// ---------------------------------------------------------------------------
// MAS forward pass v5 (R31: byte-exact revert; proven best 187us across 5
// containers; every alternative structure v7-v13 regressed).
// One wave per batch, asm-pinned 3-buffer 8-row prefetch, counted vmcnt.
// ---------------------------------------------------------------------------
#define GLOAD4(DST, PTR, OFF)                                             \
    asm volatile("global_load_dwordx4 %0, %1, off offset:" #OFF           \
                 : "=v"(DST) : "v"(PTR) : "memory")

#define GLOADD(DST, PTR)                                                  \
    asm volatile("global_load_dword %0, %1, off"                          \
                 : "=v"(DST) : "v"(PTR) : "memory")

#define WAIT_VM(N) do {                                                   \
    asm volatile("s_waitcnt vmcnt(" #N ")" ::: "memory");                 \
    __builtin_amdgcn_sched_barrier(0);                                    \
} while (0)

#define LOADG(DST, G) do {                                                \
    const char* p0_ = (const char*)nc4 + (size_t)(G) * 16384 + lane * 32; \
    const char* p2_ = p0_ + 4096;                                         \
    const char* p4_ = p0_ + 8192;                                         \
    const char* p6_ = p0_ + 12288;                                        \
    GLOAD4(DST[0],  p0_, 0);    GLOAD4(DST[1],  p0_, 16);                 \
    GLOAD4(DST[2],  p0_, 2048); GLOAD4(DST[3],  p0_, 2064);               \
    GLOAD4(DST[4],  p2_, 0);    GLOAD4(DST[5],  p2_, 16);                 \
    GLOAD4(DST[6],  p2_, 2048); GLOAD4(DST[7],  p2_, 2064);               \
    GLOAD4(DST[8],  p4_, 0);    GLOAD4(DST[9],  p4_, 16);                 \
    GLOAD4(DST[10], p4_, 2048); GLOAD4(DST[11], p4_, 2064);               \
    GLOAD4(DST[12], p6_, 0);    GLOAD4(DST[13], p6_, 16);                 \
    GLOAD4(DST[14], p6_, 2048); GLOAD4(DST[15], p6_, 2064);               \
} while (0)

#define DPROW(CUR, YB, R) do {                                                \
    int y_ = (YB) + (R);                                                      \
    float s0_ = CUR[2*(R)][0],   s1_ = CUR[2*(R)][1];                         \
    float s2_ = CUR[2*(R)][2],   s3_ = CUR[2*(R)][3];                         \
    float s4_ = CUR[2*(R)+1][0], s5_ = CUR[2*(R)+1][1];                       \
    float s6_ = CUR[2*(R)+1][2], s7_ = CUR[2*(R)+1][3];                       \
    unsigned d_ = 0;                                                          \
    if (y_ == 0) {                                                            \
        if (lane == 0) v[0] = s0_;   /* only x==0 scored on row 0 */          \
    } else {                                                                  \
        float pl_ = __int_as_float(__builtin_amdgcn_update_dpp(               \
            0, __float_as_int(v[7]), 0x138, 0xF, 0xF, false));                \
        if (lane == 0) pl_ = NEG_INF;                                         \
        float n0_ = s0_ + fmaxf(v[0], pl_);  if (pl_  > v[0]) d_ |= 1u;       \
        float n1_ = s1_ + fmaxf(v[1], v[0]); if (v[0] > v[1]) d_ |= 2u;       \
        float n2_ = s2_ + fmaxf(v[2], v[1]); if (v[1] > v[2]) d_ |= 4u;       \
        float n3_ = s3_ + fmaxf(v[3], v[2]); if (v[2] > v[3]) d_ |= 8u;       \
        float n4_ = s4_ + fmaxf(v[4], v[3]); if (v[3] > v[4]) d_ |= 16u;      \
        float n5_ = s5_ + fmaxf(v[5], v[4]); if (v[4] > v[5]) d_ |= 32u;      \
        float n6_ = s6_ + fmaxf(v[6], v[5]); if (v[5] > v[6]) d_ |= 64u;      \
        float n7_ = s7_ + fmaxf(v[7], v[6]); if (v[6] > v[7]) d_ |= 128u;     \
        v[0] = n0_; v[1] = n1_; v[2] = n2_; v[3] = n3_;                       \
        v[4] = n4_; v[5] = n5_; v[6] = n6_; v[7] = n7_;                       \
    }                                                                         \
    unsigned t_ = (unsigned)(y_ - 8 * lane);                                  \
    if (t_ < 8u) d_ |= 1u << t_;          /* fold x==y for backtrack */       \
    acc |= d_ << (((R) & 3) * 8);                                             \
    if (((R) & 3) == 3) { db32[(y_ >> 2) * 64 + lane] = acc; acc = 0; }       \
} while (0)

#define FWD_ITER(G, CUR, NXT) do {                                \
    int g_ = (G);                                                 \
    if (g_ + 2 < ng) {                                            \
        LOADG(NXT, g_ + 2);  /* prefetch 2 ahead */               \
        WAIT_VM(32);                                              \
    } else if (g_ + 1 < ng) {                                     \
        WAIT_VM(16);                                              \
    } else {                                                      \
        WAIT_VM(0);                                               \
    }                                                             \
    int yb_ = 8 * g_;                                             \
    DPROW(CUR, yb_, 0); DPROW(CUR, yb_, 1);                       \
    DPROW(CUR, yb_, 2); DPROW(CUR, yb_, 3);                       \
    DPROW(CUR, yb_, 4); DPROW(CUR, yb_, 5);                       \
    DPROW(CUR, yb_, 6); DPROW(CUR, yb_, 7);                       \
} while (0)

__global__ __launch_bounds__(64, 1) void k_fwd(const float* __restrict__ neg,
                                               const int* __restrict__ lens,
                                               uint32_t* __restrict__ dirs) {
    int b = blockIdx.x, lane = threadIdx.x;
    const float* nc4 = neg + (size_t)b * TYY * TXX;   // byte math in LOADG
    uint32_t* db32 = dirs + (size_t)b * (TYY / 4) * 64;
    int slen = lens[8 + b];
    int ng = (slen + 7) >> 3;    // 192..256 (slen >= 1536)

    float v[8];
#pragma unroll
    for (int j = 0; j < 8; ++j) v[j] = NEG_INF;
    unsigned acc = 0;

    f32x4 bufA[16], bufB[16], bufC[16];  // 3 groups in flight, asm-pinned
    LOADG(bufA, 0);
    LOADG(bufB, 1);

    for (int p = 0; p < ng; p += 3) {
        FWD_ITER(p, bufA, bufC);
        if (p + 1 < ng) FWD_ITER(p + 1, bufB, bufA);
        if (p + 2 < ng) FWD_ITER(p + 2, bufC, bufB);
    }
}

// ---------------------------------------------------------------------------
// MAS backtrack v3 (R28, proven): truly deferred packing; raw loads issued
// before the 32-step chain, packed after vmcnt(0) once latency is covered.
// Scatter + duration fused in the store step.
// ---------------------------------------------------------------------------
#define RAWLD(NR, WB, QROW) do {                                          \
    const uint32_t* p_ = db32 + (QROW) + 4 * (WB);                        \
    GLOADD(NR[0],  (p_ + 0));  GLOADD(NR[1],  (p_ + 1));                  \
    GLOADD(NR[2],  (p_ + 2));  GLOADD(NR[3],  (p_ + 3));                  \
    GLOADD(NR[4],  (p_ + 4));  GLOADD(NR[5],  (p_ + 5));                  \
    GLOADD(NR[6],  (p_ + 6));  GLOADD(NR[7],  (p_ + 7));                  \
    GLOADD(NR[8],  (p_ + 8));  GLOADD(NR[9],  (p_ + 9));                  \
    GLOADD(NR[10], (p_ + 10)); GLOADD(NR[11], (p_ + 11));                 \
} while (0)

#define PACKW(W0, W1, W2, NR, BOFF) do {                                  \
    W0 = ((NR[0]>>(BOFF))&0xffu)        | (((NR[1]>>(BOFF))&0xffu)<<8) |  \
         (((NR[2]>>(BOFF))&0xffu)<<16)  | (((NR[3]>>(BOFF))&0xffu)<<24);  \
    W1 = ((NR[4]>>(BOFF))&0xffu)        | (((NR[5]>>(BOFF))&0xffu)<<8) |  \
         (((NR[6]>>(BOFF))&0xffu)<<16)  | (((NR[7]>>(BOFF))&0xffu)<<24);  \
    W2 = ((NR[8]>>(BOFF))&0xffu)        | (((NR[9]>>(BOFF))&0xffu)<<8) |  \
         (((NR[10]>>(BOFF))&0xffu)<<16) | (((NR[11]>>(BOFF))&0xffu)<<24); \
} while (0)

__global__ __launch_bounds__(64, 1) void k_bwd(const int* __restrict__ lens,
                                               const uint32_t* __restrict__ dirs,
                                               int* __restrict__ idx_map,
                                               float* __restrict__ out) {
    int b = blockIdx.x, lane = threadIdx.x;
    const uint32_t* db32 = dirs + (size_t)b * (TYY / 4) * 64;
    int tlen = lens[b], slen = lens[8 + b];

    int idx = tlen - 1;
    int y0 = slen - 1;
    int wb;
    uint32_t W0 = 0, W1 = 0, W2 = 0;
    {   // prologue: slab-0 window (one unavoidable stall)
        int yy = y0 - lane; if (yy < 0) yy = 0;
        int qrow = (yy >> 2) * 64, boff = (yy & 3) * 8;
        int t = (idx >> 5) - 1; if (t < 0) t = 0; if (t > 13) t = 13;
        wb = t;
        uint32_t R[12];
        if (lane < 32) {
            RAWLD(R, wb, qrow);
            asm volatile("s_waitcnt vmcnt(0)" ::: "memory");
            __builtin_amdgcn_sched_barrier(0);
            PACKW(W0, W1, W2, R, boff);
        }
    }
    while (y0 >= 0) {
        int w0 = (idx >> 5) - 1; if (w0 < 0) w0 = 0; if (w0 > 14) w0 = 14;
        int s = w0 - wb; if (s < 0) s = 0; if (s > 1) s = 1;
        uint32_t lo = s ? W1 : W0;
        uint32_t hi = s ? W2 : W1;
        int base = (wb + s) << 5;
        // ---- issue next slab's RAW loads (latency hides under the chain) --
        uint32_t N[12];
        int idxm = idx - 32; if (idxm < 0) idxm = 0;
        int wbn = (idxm >> 5) - 1; if (wbn < 0) wbn = 0; if (wbn > 13) wbn = 13;
        int yn = y0 - 32 - lane; if (yn < 0) yn = 0;
        int qn = (yn >> 2) * 64, bn = (yn & 3) * 8;
        if (lane < 32) RAWLD(N, wbn, qn);
        __builtin_amdgcn_sched_barrier(0);
        // ---- 32-step chain ----
        int nsteps = (y0 + 1 < 32) ? y0 + 1 : 32;
        int cap = 0;
#pragma unroll
        for (int j = 0; j < 32; ++j) {
            if (lane == j) cap = idx;
            uint32_t l = (uint32_t)__builtin_amdgcn_readlane((int)lo, j);
            uint32_t h = (uint32_t)__builtin_amdgcn_readlane((int)hi, j);
            int bp = idx - base;              // 0..63 within slab
            uint32_t word = (bp & 32) ? h : l;
            idx -= (int)((word >> (bp & 31)) & 1u);
        }
        __builtin_amdgcn_sched_barrier(0);
        asm volatile("s_waitcnt vmcnt(0)" ::: "memory");   // N landed
        __builtin_amdgcn_sched_barrier(0);
        PACKW(W0, W1, W2, N, bn);
        wb = wbn;
        if (lane < nsteps) {
            int y = y0 - lane;
            idx_map[b * TYY + y] = cap;
            out[((size_t)(b * TYY + y)) * TXX + cap] = 1.0f;       // scatter
            atomicAdd(&out[O4 + b * TXX + cap], 1.0f);             // duration
        }
        y0 -= 32;
    }
}

// Gather m_p/logs_p onto spec frames via idx_map; fused KL partial sums.
__global__ __launch_bounds__(256) void k_gather(const float* __restrict__ z_p,
                                                const float* __restrict__ m_p,
                                                const float* __restrict__ logs_p,
                                                const float* __restrict__ logs_q,
                                                const int* __restrict__ lens,
                                                const int* __restrict__ idx_map,
                                                float* __restrict__ out,
                                                float* __restrict__ partials) {
    const int S = BB * CC * TYY / 4;
    int base = blockIdx.x * 256 + threadIdx.x;
    float klsum = 0.f;
#pragma unroll
    for (int r = 0; r < 4; ++r) {
        int i = base + r * S;
        int t = i & (TYY - 1);
        int bc = i >> 11;
        int b = bc / CC;
        float ma = 0.f, la = 0.f;
        if (t < lens[8 + b]) {
            int x = idx_map[b * TYY + t];
            size_t off = (size_t)bc * TXX + x;
            ma = m_p[off];
            la = logs_p[off];
            float zv = z_p[i], lq = logs_q[i];
            float dz = zv - ma;
            klsum += la - lq - 0.5f + 0.5f * dz * dz * expf(-2.0f * la);
        }
        out[O1 + i] = ma;
        out[O2 + i] = la;
    }
    for (int o = 32; o > 0; o >>= 1) klsum += __shfl_down(klsum, o);
    __shared__ float red[4];
    if ((threadIdx.x & 63) == 0) red[threadIdx.x >> 6] = klsum;
    __syncthreads();
    if (threadIdx.x == 0) partials[blockIdx.x] = red[0] + red[1] + red[2] + red[3];
}

__global__ void k_final(const float* __restrict__ partials, const int* __restrict__ lens,
                        float* __restrict__ out) {
    float s = 0.f;
    for (int i = threadIdx.x; i < 3072; i += 256) s += partials[i];
    for (int o = 32; o > 0; o >>= 1) s += __shfl_down(s, o);
    __shared__ float red[4];
    if ((threadIdx.x & 63) == 0) red[threadIdx.x >> 6] = s;
    __syncthreads();
    if (threadIdx.x == 0) {
        float tot = 0.f;
        for (int b = 0; b < 8; ++b) tot += (float)lens[8 + b];
        out[O3] = (red[0] + red[1] + red[2] + red[3]) / tot;
    }
}

extern "C" void kernel_launch(void* const* d_in, const int* in_sizes, int n_in,
                              void* d_out, int out_size, void* d_ws, size_t ws_size,
                              hipStream_t stream) {
    const float* z_p    = (const float*)d_in[0];
    const float* m_p    = (const float*)d_in[1];
    const float* logs_p = (const float*)d_in[2];
    const float* logs_q = (const float*)d_in[3];
    const float* tmask  = (const float*)d_in[4];
    const float* smask  = (const float*)d_in[5];
    float* out = (float*)d_out;
    char* ws = (char*)d_ws;

    float*    neg      = (float*)(ws + WS_NEG);
    float*    sarr     = (float*)(ws + WS_S);
    float*    msr      = (float*)(ws + WS_MSR);
    float*    bias     = (float*)(ws + WS_BIAS);
    uint32_t* dirs     = (uint32_t*)(ws + WS_DIRS);
    int*      idx_map  = (int*)(ws + WS_IDX);
    int*      lens     = (int*)(ws + WS_LENS);
    float*    partials = (float*)(ws + WS_PART);

    hipLaunchKernelGGL(k_pre,    dim3(PRE_NPREP + PRE_NBIAS + PRE_NLEN),
                       dim3(256), 0, stream,
                       logs_p, m_p, tmask, smask, sarr, msr, bias, lens);
    hipLaunchKernelGGL(k_gz,     dim3(GZ_NZERO + 2048), dim3(128), 0, stream,
                       z_p, msr, sarr, bias, lens, neg, out);
    hipLaunchKernelGGL(k_fwd,    dim3(8),        dim3(64),  0, stream, neg, lens, dirs);
    hipLaunchKernelGGL(k_bwd,    dim3(8),        dim3(64),  0, stream, lens, dirs, idx_map, out);
    hipLaunchKernelGGL(k_gather, dim3(3072),     dim3(256), 0, stream,
                       z_p, m_p, logs_p, logs_q, lens, idx_map, out, partials);
    hipLaunchKernelGGL(k_final,  dim3(1),        dim3(256), 0, stream, partials, lens, out);
}

// Round 18
// 489.680 us; speedup vs baseline: 1.1192x; 1.0464x over previous
//
#include <hip/hip_runtime.h>
#include <cstdint>
#include <cstddef>

// Problem shape (fixed by the reference): B=8, C=192, Tx=512, Ty=2048.
#define BB 8
#define CC 192
#define TXX 512
#define TYY 2048

#define NEG_INF (-1e9f)
#define HALF_LOG_2PI 0.9189385332046727f  // 0.5*log(2*pi)

// ---- output layout (floats, concatenated in return order) ----
#define O1 8388608
#define O2 11534336
#define O3 14680064
#define O4 14680065

// ---- workspace layout (bytes) ----
#define WS_NEG   0           // neg_cent fp32 [B,Ty,Tx]           33,554,432 B
#define WS_S     33554432    // s_p_sq_r [B,C,Tx]                  3,145,728 B
#define WS_MSR   36700160    // m_p * s  [B,C,Tx]                  3,145,728 B
#define WS_BIAS  39845888    // nc1+nc4  [B,Tx]                       16,384 B
#define WS_DIRS  39862272    // dir bits [B,Ty/4,64] dwords        1,048,576 B
#define WS_IDX   40910848    // idx_map  [B,Ty] int                   65,536 B
#define WS_LENS  40976384    // int text_len[8], spec_len[8]             64 B
#define WS_PART  40976448    // kl partials [3072] float              12,288 B

typedef float f32x4 __attribute__((ext_vector_type(4)));

// ---------------------------------------------------------------------------
// k_pre (R28, proven): fused prep + bias + len. bias recomputes msv with the
// IDENTICAL expression tree as prep stores (bitwise-same).
// ---------------------------------------------------------------------------
#define PRE_NPREP 3072
#define PRE_NBIAS 16
#define PRE_NLEN  8
__global__ __launch_bounds__(256) void k_pre(const float* __restrict__ logs_p,
                                             const float* __restrict__ m_p,
                                             const float* __restrict__ tmask,
                                             const float* __restrict__ smask,
                                             float* __restrict__ s,
                                             float* __restrict__ msr,
                                             float* __restrict__ bias,
                                             int* __restrict__ lens) {
    int blk = blockIdx.x, tid = threadIdx.x;
    if (blk < PRE_NPREP) {
        int i = blk * 256 + tid;
        float lp = logs_p[i], m = m_p[i];
        float sv = expf(-2.0f * lp);
        s[i] = sv;
        msr[i] = m * sv;
    } else if (blk < PRE_NPREP + PRE_NBIAS) {
        int i = (blk - PRE_NPREP) * 256 + tid;  // B*Tx = 4096
        int b = i >> 9, x = i & (TXX - 1);
        size_t base = (size_t)b * CC * TXX + x;
        const float* lpb = logs_p + base;
        const float* mb  = m_p + base;
        float acc = 0.f;
#pragma unroll 8
        for (int c = 0; c < CC; ++c) {
            float lp = lpb[(size_t)c * TXX];
            float m  = mb[(size_t)c * TXX];
            float msv = m * expf(-2.0f * lp);   // == msr[c] bitwise
            acc += -HALF_LOG_2PI - lp - 0.5f * m * msv;
        }
        bias[i] = acc;
    } else {
        __shared__ float red[256];
        int b = blk - (PRE_NPREP + PRE_NBIAS);
        float ts = 0.f;
        for (int i = tid; i < TXX; i += 256) ts += tmask[b * TXX + i];
        red[tid] = ts; __syncthreads();
        for (int s2 = 128; s2 > 0; s2 >>= 1) { if (tid < s2) red[tid] += red[tid + s2]; __syncthreads(); }
        if (tid == 0) lens[b] = (int)(red[0] + 0.5f);
        __syncthreads();
        float ss = 0.f;
        for (int i = tid; i < TYY; i += 256) ss += smask[b * TYY + i];
        red[tid] = ss; __syncthreads();
        for (int s2 = 128; s2 > 0; s2 >>= 1) { if (tid < s2) red[tid] += red[tid + s2]; __syncthreads(); }
        if (tid == 0) lens[8 + b] = (int)(red[0] + 0.5f);
    }
}

// ---------------------------------------------------------------------------
// k_gz v2 (R29, proven best; R32 revert from the 128-thread v3 which cost
// +24us via occupancy loss): zero blocks (0..511) + 64x64 gemm 256-thread
// with register double-buffered staging (512..2559). Bitwise-identical neg.
// ---------------------------------------------------------------------------
#define GZ_NZERO 512
__global__ __launch_bounds__(256) void k_gz(const float* __restrict__ z,
                                            const float* __restrict__ msr,
                                            const float* __restrict__ sarr,
                                            const float* __restrict__ bias,
                                            const int* __restrict__ lens,
                                            float* __restrict__ neg,
                                            float* __restrict__ out) {
    int id = blockIdx.x, tid = threadIdx.x;
    if (id < GZ_NZERO) {
        int64_t i = (int64_t)id * 256 + tid;
        const int64_t n4 = (int64_t)BB * TYY * TXX / 4;
        float4 z4 = make_float4(0.f, 0.f, 0.f, 0.f);
        float4* p4 = (float4*)out;
        for (int64_t k = i; k < n4; k += (int64_t)GZ_NZERO * 256) p4[k] = z4;
        if (i < BB * TXX) out[O4 + i] = 0.0f;
        return;
    }
    int gid = id - GZ_NZERO;
    int x0 = (gid & 7) * 64, t0 = ((gid >> 3) & 31) * 64, b = gid >> 8;
    if (x0 >= lens[b] || t0 >= lens[8 + b]) return;   // masked tile

    __shared__ float Zs[16][68], Ms[16][68], Ss[16][68];  // +4 pad
    int tx = tid & 15, ty = tid >> 4;
    const float* zb = z    + (size_t)b * CC * TYY;
    const float* mb = msr  + (size_t)b * CC * TXX;
    const float* sb = sarr + (size_t)b * CC * TXX;
    int lr = tid >> 4, lc = (tid & 15) * 4;
    float acc[4][4] = {};
    float4 zv = *(const float4*)(zb + (size_t)lr * TYY + t0 + lc);
    float4 mv = *(const float4*)(mb + (size_t)lr * TXX + x0 + lc);
    float4 sv = *(const float4*)(sb + (size_t)lr * TXX + x0 + lc);
    for (int k0 = 0; k0 < CC; k0 += 16) {
        __syncthreads();
        *(float4*)&Zs[lr][lc] = zv;
        *(float4*)&Ms[lr][lc] = mv;
        *(float4*)&Ss[lr][lc] = sv;
        __syncthreads();
        if (k0 + 16 < CC) {
            zv = *(const float4*)(zb + (size_t)(k0 + 16 + lr) * TYY + t0 + lc);
            mv = *(const float4*)(mb + (size_t)(k0 + 16 + lr) * TXX + x0 + lc);
            sv = *(const float4*)(sb + (size_t)(k0 + 16 + lr) * TXX + x0 + lc);
        }
#pragma unroll
        for (int k = 0; k < 16; ++k) {
            float4 a4  = *(const float4*)&Zs[k][ty * 4];
            float4 bm4 = *(const float4*)&Ms[k][tx * 4];
            float4 bs4 = *(const float4*)&Ss[k][tx * 4];
            float av[4]  = {a4.x, a4.y, a4.z, a4.w};
            float bmv[4] = {bm4.x, bm4.y, bm4.z, bm4.w};
            float bsv[4] = {bs4.x, bs4.y, bs4.z, bs4.w};
#pragma unroll
            for (int i2 = 0; i2 < 4; ++i2) {
                float a2 = -0.5f * av[i2] * av[i2];
#pragma unroll
                for (int j = 0; j < 4; ++j)
                    acc[i2][j] += av[i2] * bmv[j] + a2 * bsv[j];
            }
        }
    }
    float4 b4 = *(const float4*)(bias + b * TXX + x0 + tx * 4);
    float bv[4] = {b4.x, b4.y, b4.z, b4.w};
#pragma unroll
    for (int i2 = 0; i2 < 4; ++i2) {
        int t = t0 + ty * 4 + i2;
        float4 o;
        o.x = acc[i2][0] + bv[0]; o.y = acc[i2][1] + bv[1];
        o.z = acc[i2][2] + bv[2]; o.w = acc[i2][3] + bv[3];
        *(float4*)(neg + ((size_t)b * TYY + t) * TXX + x0 + tx * 4) = o;
    }
}

// ---------------------------------------------------------------------------
// MAS forward v5 (proven best, 187.3us across 6 containers) + bwd v3 fused
// as the tail (R32; fusion mechanism proven correct in R20/R22/R23).
// Same-wave dirs store->load ordering guaranteed by WAIT_VM(0) before the
// backtrack. Saves one dispatch + launch gap; dirs L2-hot.
// ---------------------------------------------------------------------------
#define GLOAD4(DST, PTR, OFF)                                             \
    asm volatile("global_load_dwordx4 %0, %1, off offset:" #OFF           \
                 : "=v"(DST) : "v"(PTR) : "memory")

#define GLOADD(DST, PTR)                                                  \
    asm volatile("global_load_dword %0, %1, off"                          \
                 : "=v"(DST) : "v"(PTR) : "memory")

#define WAIT_VM(N) do {                                                   \
    asm volatile("s_waitcnt vmcnt(" #N ")" ::: "memory");                 \
    __builtin_amdgcn_sched_barrier(0);                                    \
} while (0)

#define LOADG(DST, G) do {                                                \
    const char* p0_ = (const char*)nc4 + (size_t)(G) * 16384 + lane * 32; \
    const char* p2_ = p0_ + 4096;                                         \
    const char* p4_ = p0_ + 8192;                                         \
    const char* p6_ = p0_ + 12288;                                        \
    GLOAD4(DST[0],  p0_, 0);    GLOAD4(DST[1],  p0_, 16);                 \
    GLOAD4(DST[2],  p0_, 2048); GLOAD4(DST[3],  p0_, 2064);               \
    GLOAD4(DST[4],  p2_, 0);    GLOAD4(DST[5],  p2_, 16);                 \
    GLOAD4(DST[6],  p2_, 2048); GLOAD4(DST[7],  p2_, 2064);               \
    GLOAD4(DST[8],  p4_, 0);    GLOAD4(DST[9],  p4_, 16);                 \
    GLOAD4(DST[10], p4_, 2048); GLOAD4(DST[11], p4_, 2064);               \
    GLOAD4(DST[12], p6_, 0);    GLOAD4(DST[13], p6_, 16);                 \
    GLOAD4(DST[14], p6_, 2048); GLOAD4(DST[15], p6_, 2064);               \
} while (0)

#define DPROW(CUR, YB, R) do {                                                \
    int y_ = (YB) + (R);                                                      \
    float s0_ = CUR[2*(R)][0],   s1_ = CUR[2*(R)][1];                         \
    float s2_ = CUR[2*(R)][2],   s3_ = CUR[2*(R)][3];                         \
    float s4_ = CUR[2*(R)+1][0], s5_ = CUR[2*(R)+1][1];                       \
    float s6_ = CUR[2*(R)+1][2], s7_ = CUR[2*(R)+1][3];                       \
    unsigned d_ = 0;                                                          \
    if (y_ == 0) {                                                            \
        if (lane == 0) v[0] = s0_;   /* only x==0 scored on row 0 */          \
    } else {                                                                  \
        float pl_ = __int_as_float(__builtin_amdgcn_update_dpp(               \
            0, __float_as_int(v[7]), 0x138, 0xF, 0xF, false));                \
        if (lane == 0) pl_ = NEG_INF;                                         \
        float n0_ = s0_ + fmaxf(v[0], pl_);  if (pl_  > v[0]) d_ |= 1u;       \
        float n1_ = s1_ + fmaxf(v[1], v[0]); if (v[0] > v[1]) d_ |= 2u;       \
        float n2_ = s2_ + fmaxf(v[2], v[1]); if (v[1] > v[2]) d_ |= 4u;       \
        float n3_ = s3_ + fmaxf(v[3], v[2]); if (v[2] > v[3]) d_ |= 8u;       \
        float n4_ = s4_ + fmaxf(v[4], v[3]); if (v[3] > v[4]) d_ |= 16u;      \
        float n5_ = s5_ + fmaxf(v[5], v[4]); if (v[4] > v[5]) d_ |= 32u;      \
        float n6_ = s6_ + fmaxf(v[6], v[5]); if (v[5] > v[6]) d_ |= 64u;      \
        float n7_ = s7_ + fmaxf(v[7], v[6]); if (v[6] > v[7]) d_ |= 128u;     \
        v[0] = n0_; v[1] = n1_; v[2] = n2_; v[3] = n3_;                       \
        v[4] = n4_; v[5] = n5_; v[6] = n6_; v[7] = n7_;                       \
    }                                                                         \
    unsigned t_ = (unsigned)(y_ - 8 * lane);                                  \
    if (t_ < 8u) d_ |= 1u << t_;          /* fold x==y for backtrack */       \
    acc |= d_ << (((R) & 3) * 8);                                             \
    if (((R) & 3) == 3) { db32[(y_ >> 2) * 64 + lane] = acc; acc = 0; }       \
} while (0)

#define FWD_ITER(G, CUR, NXT) do {                                \
    int g_ = (G);                                                 \
    if (g_ + 2 < ng) {                                            \
        LOADG(NXT, g_ + 2);  /* prefetch 2 ahead */               \
        WAIT_VM(32);                                              \
    } else if (g_ + 1 < ng) {                                     \
        WAIT_VM(16);                                              \
    } else {                                                      \
        WAIT_VM(0);                                               \
    }                                                             \
    int yb_ = 8 * g_;                                             \
    DPROW(CUR, yb_, 0); DPROW(CUR, yb_, 1);                       \
    DPROW(CUR, yb_, 2); DPROW(CUR, yb_, 3);                       \
    DPROW(CUR, yb_, 4); DPROW(CUR, yb_, 5);                       \
    DPROW(CUR, yb_, 6); DPROW(CUR, yb_, 7);                       \
} while (0)

#define RAWLD(NR, WB, QROW) do {                                          \
    const uint32_t* p_ = db32 + (QROW) + 4 * (WB);                        \
    GLOADD(NR[0],  (p_ + 0));  GLOADD(NR[1],  (p_ + 1));                  \
    GLOADD(NR[2],  (p_ + 2));  GLOADD(NR[3],  (p_ + 3));                  \
    GLOADD(NR[4],  (p_ + 4));  GLOADD(NR[5],  (p_ + 5));                  \
    GLOADD(NR[6],  (p_ + 6));  GLOADD(NR[7],  (p_ + 7));                  \
    GLOADD(NR[8],  (p_ + 8));  GLOADD(NR[9],  (p_ + 9));                  \
    GLOADD(NR[10], (p_ + 10)); GLOADD(NR[11], (p_ + 11));                 \
} while (0)

#define PACKW(W0, W1, W2, NR, BOFF) do {                                  \
    W0 = ((NR[0]>>(BOFF))&0xffu)        | (((NR[1]>>(BOFF))&0xffu)<<8) |  \
         (((NR[2]>>(BOFF))&0xffu)<<16)  | (((NR[3]>>(BOFF))&0xffu)<<24);  \
    W1 = ((NR[4]>>(BOFF))&0xffu)        | (((NR[5]>>(BOFF))&0xffu)<<8) |  \
         (((NR[6]>>(BOFF))&0xffu)<<16)  | (((NR[7]>>(BOFF))&0xffu)<<24);  \
    W2 = ((NR[8]>>(BOFF))&0xffu)        | (((NR[9]>>(BOFF))&0xffu)<<8) |  \
         (((NR[10]>>(BOFF))&0xffu)<<16) | (((NR[11]>>(BOFF))&0xffu)<<24); \
} while (0)

__global__ __launch_bounds__(64, 1) void k_fwd(const float* __restrict__ neg,
                                               const int* __restrict__ lens,
                                               uint32_t* __restrict__ dirs,
                                               int* __restrict__ idx_map,
                                               float* __restrict__ out) {
    int b = blockIdx.x, lane = threadIdx.x;
    const float* nc4 = neg + (size_t)b * TYY * TXX;   // byte math in LOADG
    uint32_t* db32 = dirs + (size_t)b * (TYY / 4) * 64;
    int slen = lens[8 + b];
    int ng = (slen + 7) >> 3;    // 192..256 (slen >= 1536)

    float v[8];
#pragma unroll
    for (int j = 0; j < 8; ++j) v[j] = NEG_INF;
    unsigned acc = 0;

    f32x4 bufA[16], bufB[16], bufC[16];  // 3 groups in flight, asm-pinned
    LOADG(bufA, 0);
    LOADG(bufB, 1);

    for (int p = 0; p < ng; p += 3) {
        FWD_ITER(p, bufA, bufC);
        if (p + 1 < ng) FWD_ITER(p + 1, bufB, bufA);
        if (p + 2 < ng) FWD_ITER(p + 2, bufC, bufB);
    }

    // ---- fused backtrack (bwd v3, R28-proven); dirs stores drained first --
    WAIT_VM(0);
    {
        int tlen = lens[b];
        int idx = tlen - 1;
        int y0 = slen - 1;
        int wb;
        uint32_t W0 = 0, W1 = 0, W2 = 0;
        {   // prologue: slab-0 window (one unavoidable stall)
            int yy = y0 - lane; if (yy < 0) yy = 0;
            int qrow = (yy >> 2) * 64, boff = (yy & 3) * 8;
            int t = (idx >> 5) - 1; if (t < 0) t = 0; if (t > 13) t = 13;
            wb = t;
            uint32_t R[12];
            if (lane < 32) {
                RAWLD(R, wb, qrow);
                asm volatile("s_waitcnt vmcnt(0)" ::: "memory");
                __builtin_amdgcn_sched_barrier(0);
                PACKW(W0, W1, W2, R, boff);
            }
        }
        while (y0 >= 0) {
            int w0 = (idx >> 5) - 1; if (w0 < 0) w0 = 0; if (w0 > 14) w0 = 14;
            int s = w0 - wb; if (s < 0) s = 0; if (s > 1) s = 1;
            uint32_t lo = s ? W1 : W0;
            uint32_t hi = s ? W2 : W1;
            int base = (wb + s) << 5;
            // ---- issue next slab's RAW loads (hide under the chain) ----
            uint32_t N[12];
            int idxm = idx - 32; if (idxm < 0) idxm = 0;
            int wbn = (idxm >> 5) - 1; if (wbn < 0) wbn = 0; if (wbn > 13) wbn = 13;
            int yn = y0 - 32 - lane; if (yn < 0) yn = 0;
            int qn = (yn >> 2) * 64, bn = (yn & 3) * 8;
            if (lane < 32) RAWLD(N, wbn, qn);
            __builtin_amdgcn_sched_barrier(0);
            // ---- 32-step chain ----
            int nsteps = (y0 + 1 < 32) ? y0 + 1 : 32;
            int cap = 0;
#pragma unroll
            for (int j = 0; j < 32; ++j) {
                if (lane == j) cap = idx;
                uint32_t l = (uint32_t)__builtin_amdgcn_readlane((int)lo, j);
                uint32_t h = (uint32_t)__builtin_amdgcn_readlane((int)hi, j);
                int bp = idx - base;              // 0..63 within slab
                uint32_t word = (bp & 32) ? h : l;
                idx -= (int)((word >> (bp & 31)) & 1u);
            }
            __builtin_amdgcn_sched_barrier(0);
            asm volatile("s_waitcnt vmcnt(0)" ::: "memory");   // N landed
            __builtin_amdgcn_sched_barrier(0);
            PACKW(W0, W1, W2, N, bn);
            wb = wbn;
            if (lane < nsteps) {
                int y = y0 - lane;
                idx_map[b * TYY + y] = cap;
                out[((size_t)(b * TYY + y)) * TXX + cap] = 1.0f;   // scatter
                atomicAdd(&out[O4 + b * TXX + cap], 1.0f);         // duration
            }
            y0 -= 32;
        }
    }
}

// Gather m_p/logs_p onto spec frames via idx_map; fused KL partial sums.
__global__ __launch_bounds__(256) void k_gather(const float* __restrict__ z_p,
                                                const float* __restrict__ m_p,
                                                const float* __restrict__ logs_p,
                                                const float* __restrict__ logs_q,
                                                const int* __restrict__ lens,
                                                const int* __restrict__ idx_map,
                                                float* __restrict__ out,
                                                float* __restrict__ partials) {
    const int S = BB * CC * TYY / 4;
    int base = blockIdx.x * 256 + threadIdx.x;
    float klsum = 0.f;
#pragma unroll
    for (int r = 0; r < 4; ++r) {
        int i = base + r * S;
        int t = i & (TYY - 1);
        int bc = i >> 11;
        int b = bc / CC;
        float ma = 0.f, la = 0.f;
        if (t < lens[8 + b]) {
            int x = idx_map[b * TYY + t];
            size_t off = (size_t)bc * TXX + x;
            ma = m_p[off];
            la = logs_p[off];
            float zv = z_p[i], lq = logs_q[i];
            float dz = zv - ma;
            klsum += la - lq - 0.5f + 0.5f * dz * dz * expf(-2.0f * la);
        }
        out[O1 + i] = ma;
        out[O2 + i] = la;
    }
    for (int o = 32; o > 0; o >>= 1) klsum += __shfl_down(klsum, o);
    __shared__ float red[4];
    if ((threadIdx.x & 63) == 0) red[threadIdx.x >> 6] = klsum;
    __syncthreads();
    if (threadIdx.x == 0) partials[blockIdx.x] = red[0] + red[1] + red[2] + red[3];
}

__global__ void k_final(const float* __restrict__ partials, const int* __restrict__ lens,
                        float* __restrict__ out) {
    float s = 0.f;
    for (int i = threadIdx.x; i < 3072; i += 256) s += partials[i];
    for (int o = 32; o > 0; o >>= 1) s += __shfl_down(s, o);
    __shared__ float red[4];
    if ((threadIdx.x & 63) == 0) red[threadIdx.x >> 6] = s;
    __syncthreads();
    if (threadIdx.x == 0) {
        float tot = 0.f;
        for (int b = 0; b < 8; ++b) tot += (float)lens[8 + b];
        out[O3] = (red[0] + red[1] + red[2] + red[3]) / tot;
    }
}

extern "C" void kernel_launch(void* const* d_in, const int* in_sizes, int n_in,
                              void* d_out, int out_size, void* d_ws, size_t ws_size,
                              hipStream_t stream) {
    const float* z_p    = (const float*)d_in[0];
    const float* m_p    = (const float*)d_in[1];
    const float* logs_p = (const float*)d_in[2];
    const float* logs_q = (const float*)d_in[3];
    const float* tmask  = (const float*)d_in[4];
    const float* smask  = (const float*)d_in[5];
    float* out = (float*)d_out;
    char* ws = (char*)d_ws;

    float*    neg      = (float*)(ws + WS_NEG);
    float*    sarr     = (float*)(ws + WS_S);
    float*    msr      = (float*)(ws + WS_MSR);
    float*    bias     = (float*)(ws + WS_BIAS);
    uint32_t* dirs     = (uint32_t*)(ws + WS_DIRS);
    int*      idx_map  = (int*)(ws + WS_IDX);
    int*      lens     = (int*)(ws + WS_LENS);
    float*    partials = (float*)(ws + WS_PART);

    hipLaunchKernelGGL(k_pre,    dim3(PRE_NPREP + PRE_NBIAS + PRE_NLEN),
                       dim3(256), 0, stream,
                       logs_p, m_p, tmask, smask, sarr, msr, bias, lens);
    hipLaunchKernelGGL(k_gz,     dim3(GZ_NZERO + 2048), dim3(256), 0, stream,
                       z_p, msr, sarr, bias, lens, neg, out);
    hipLaunchKernelGGL(k_fwd,    dim3(8),        dim3(64),  0, stream,
                       neg, lens, dirs, idx_map, out);
    hipLaunchKernelGGL(k_gather, dim3(3072),     dim3(256), 0, stream,
                       z_p, m_p, logs_p, logs_q, lens, idx_map, out, partials);
    hipLaunchKernelGGL(k_final,  dim3(1),        dim3(256), 0, stream, partials, lens, out);
}